// Round 3
// baseline (1568.310 us; speedup 1.0000x reference)
//
#include <hip/hip_runtime.h>
#include <hip/hip_bf16.h>
#include <math.h>

typedef unsigned short u16;
typedef __bf16 bf16x8 __attribute__((ext_vector_type(8)));
typedef float f32x4 __attribute__((ext_vector_type(4)));

#define B_  2
#define S_  2048
#define D_  4096
#define H_  32
#define HD_ 128

__device__ __forceinline__ unsigned rne_bf16(float x) {
  unsigned u = __float_as_uint(x);
  return (u + 0x7fffu + ((u >> 16) & 1u)) >> 16;
}

__device__ __forceinline__ void async16(void* lds_p, const void* g) {
  __builtin_amdgcn_global_load_lds(
      (__attribute__((address_space(1))) void*)(g),
      (__attribute__((address_space(3))) void*)(lds_p), 16, 0, 0);
}

// ---------------------------------------------------------------- convert
__global__ __launch_bounds__(256) void convert_bf16(
    const float* __restrict__ src, u16* __restrict__ dst, int n8) {
  int i = blockIdx.x * 256 + threadIdx.x;
  if (i >= n8) return;
  const float4* s = (const float4*)src + (size_t)i * 2;
  float4 a = s[0], b = s[1];
  uint4 o;
  o.x = rne_bf16(a.x) | (rne_bf16(a.y) << 16);
  o.y = rne_bf16(a.z) | (rne_bf16(a.w) << 16);
  o.z = rne_bf16(b.x) | (rne_bf16(b.y) << 16);
  o.w = rne_bf16(b.z) | (rne_bf16(b.w) << 16);
  ((uint4*)dst)[i] = o;
}

// fused 4-tensor convert (all four are 16.8M floats): saves 3 launch gaps
__global__ __launch_bounds__(256) void convert_bf16_x4(
    const float* __restrict__ s0, const float* __restrict__ s1,
    const float* __restrict__ s2, const float* __restrict__ s3,
    u16* __restrict__ d0, u16* __restrict__ d1,
    u16* __restrict__ d2, u16* __restrict__ d3) {
  const int per = (B_ * S_ * D_) / 8 / 256;  // blocks per tensor
  const int which = blockIdx.x / per;
  const int i = (blockIdx.x % per) * 256 + threadIdx.x;
  const float* src = which == 0 ? s0 : which == 1 ? s1 : which == 2 ? s2 : s3;
  u16* dst = which == 0 ? d0 : which == 1 ? d1 : which == 2 ? d2 : d3;
  const float4* s = (const float4*)src + (size_t)i * 2;
  float4 a = s[0], b = s[1];
  uint4 o;
  o.x = rne_bf16(a.x) | (rne_bf16(a.y) << 16);
  o.y = rne_bf16(a.z) | (rne_bf16(a.w) << 16);
  o.z = rne_bf16(b.x) | (rne_bf16(b.y) << 16);
  o.w = rne_bf16(b.z) | (rne_bf16(b.w) << 16);
  ((uint4*)dst)[i] = o;
}

// ---------------------------------------------------------------- GEMM
// 256x256 tile, BK=64, 8 waves (2x4), 8-phase schedule with counted vmcnt.
// RETRY of the R1 port with the R1 failure mechanism addressed: barriers are
// __builtin_amdgcn_s_barrier() (NOT asm "s_barrier" with memory clobber,
// which let the compiler conservatively drain vmcnt(0) per phase -> the
// observed 16.5% MfmaUtil). vmcnt waits stay as asm w/ memory clobber
// (2 per K-tile, cheap; blocks illegal reordering of DS/VMEM across them).
// Schedule + full WAR/ledger audit as in R1 (correctness-verified there).
#define WGBAR() __builtin_amdgcn_s_barrier()
#define LGKM0() do { asm volatile("s_waitcnt lgkmcnt(0)" ::: "memory"); \
                     __builtin_amdgcn_sched_barrier(0); } while (0)
#define VMW(N)  asm volatile("s_waitcnt vmcnt(" #N ")" ::: "memory")

#define STAGE_A(P, HH, T) do { \
  async16(&lds[(P) * 32768 + (HH) * 8192 + c0 * 8], Ag[HH][0] + (size_t)(T) * 64); \
  async16(&lds[(P) * 32768 + (HH) * 8192 + c1 * 8], Ag[HH][1] + (size_t)(T) * 64); \
} while (0)
#define STAGE_B(P, HH, T) do { \
  async16(&lds[(P) * 32768 + 16384 + (HH) * 8192 + c0 * 8], Bg[HH][0] + (size_t)(T) * 64); \
  async16(&lds[(P) * 32768 + 16384 + (HH) * 8192 + c1 * 8], Bg[HH][1] + (size_t)(T) * 64); \
} while (0)

#define READ_A(dst, P, MH) do { \
  _Pragma("unroll") for (int i_ = 0; i_ < 4; ++i_) \
  _Pragma("unroll") for (int kk_ = 0; kk_ < 2; ++kk_) \
    dst[i_][kk_] = *(const bf16x8*)&lds[(P) * 32768 + ((MH) * 4 + i_) * 1024 + aoff[kk_]]; \
} while (0)
#define READ_B(dst, P, NH) do { \
  _Pragma("unroll") for (int j_ = 0; j_ < 2; ++j_) \
  _Pragma("unroll") for (int kk_ = 0; kk_ < 2; ++kk_) \
    dst[j_][kk_] = *(const bf16x8*)&lds[(P) * 32768 + ((NH) * 2 + j_) * 1024 + boff[kk_]]; \
} while (0)

#define MFMA_Q(AF, BF, IB, JB) do { \
  __builtin_amdgcn_s_setprio(1); \
  _Pragma("unroll") for (int kk_ = 0; kk_ < 2; ++kk_) \
  _Pragma("unroll") for (int i_ = 0; i_ < 4; ++i_) \
  _Pragma("unroll") for (int j_ = 0; j_ < 2; ++j_) \
    acc[(IB) + i_][(JB) + j_] = __builtin_amdgcn_mfma_f32_16x16x32_bf16( \
        AF[i_][kk_], BF[j_][kk_], acc[(IB) + i_][(JB) + j_], 0, 0, 0); \
  __builtin_amdgcn_s_setprio(0); \
} while (0)

template <int MODE>
__global__ __launch_bounds__(512, 2) void gemm_bt(
    const u16* __restrict__ A, const u16* __restrict__ Bw,
    u16* __restrict__ outB, float* __restrict__ outF,
    const float* __restrict__ fc, const float* __restrict__ fs) {
  __shared__ __align__(16) u16 lds[65536];  // 128 KiB

  const int tid = threadIdx.x;
  const int lane = tid & 63;
  const int w = tid >> 6;
  const int lm = lane & 15, quad = lane >> 4;
  const int wr = w >> 2, wc = w & 3;
  const int K = 4096;
  const int NKT = K / 64;  // 64

  // T1: XCD rect map — XCD x owns a 4-row x 8-col rectangle of the 16x16
  // 256-tile grid (bijective; co-scheduled K-slab working set fits L2).
  const int bid = blockIdx.x;
  const int x = bid & 7, l = bid >> 3;
  const int m0 = ((x & 3) * 4 + (l & 3)) * 256;
  const int n0 = ((x >> 2) * 8 + (l >> 2)) * 256;

  // ---- staging pointers (inverse-swizzled global source, linear LDS dest)
  const int c0 = tid, c1 = tid + 512;
  const int rl0 = c0 >> 3, s0 = ((c0 & 7) ^ (rl0 & 7)) * 8;
  const int rl1 = c1 >> 3, s1 = ((c1 & 7) ^ (rl1 & 7)) * 8;
  const u16* Ag[2][2];
  const u16* Bg[2][2];
#pragma unroll
  for (int hh = 0; hh < 2; ++hh) {
    Ag[hh][0] = A + (size_t)(m0 + hh * 128 + rl0) * K + s0;
    Ag[hh][1] = A + (size_t)(m0 + hh * 128 + rl1) * K + s1;
    Bg[hh][0] = Bw + (size_t)(n0 + hh * 128 + rl0) * K + s0;
    Bg[hh][1] = Bw + (size_t)(n0 + hh * 128 + rl1) * K + s1;
  }

  // ---- frag read offsets (u16 units), swizzled slot = (kk*4+quad)^(lm&7)
  int aoff[2], boff[2];
#pragma unroll
  for (int kk = 0; kk < 2; ++kk) {
    const int sw = ((kk * 4 + quad) ^ (lm & 7)) * 8;
    aoff[kk] = (wr * 128 + lm) * 64 + sw;
    boff[kk] = 16384 + (wc * 64 + lm) * 64 + sw;
  }

  bf16x8 aA[4][2], aB[4][2], b0r[2][2], b1r[2][2];
  f32x4 acc[8][4] = {};

  // ---- prologue: kt0 full (4 ht) + kt1 {Bh0, Ah0, Ah1}; 14 loads in flight
  STAGE_A(0, 0, 0); STAGE_A(0, 1, 0); STAGE_B(0, 0, 0); STAGE_B(0, 1, 0);
  STAGE_B(1, 0, 1); STAGE_A(1, 0, 1); STAGE_A(1, 1, 1);
  VMW(6);   // kt0's 8 loads complete; kt1's 3 ht stay in flight
  WGBAR();
  READ_A(aA, 0, 0);   // A[mh0] kt0
  READ_B(b0r, 0, 0);  // B[nh0] kt0

  for (int kt = 0; kt < NKT - 2; kt += 2) {
    // ======== tile kt (buf0): aA=mh0(kt), b0r=nh0(kt)
    // C1
    READ_B(b1r, 0, 1);            // nh1(kt)
    STAGE_B(1, 1, kt + 1);        // (kt+1).Bh1
    WGBAR(); LGKM0();
    MFMA_Q(aA, b0r, 0, 0);
    WGBAR();
    // C2
    READ_A(aB, 0, 1);             // mh1(kt)
    STAGE_B(0, 0, kt + 2);        // (kt+2).Bh0
    WGBAR(); LGKM0();
    MFMA_Q(aA, b1r, 0, 2);
    VMW(4);                       // completes (kt+1).Ah1 and older
    WGBAR();
    // C3
    READ_A(aA, 1, 0);             // mh0(kt+1) from buf1
    STAGE_A(0, 0, kt + 2);        // (kt+2).Ah0
    WGBAR(); LGKM0();
    MFMA_Q(aB, b1r, 4, 2);
    VMW(4);                       // completes (kt+1).Bh1 and older
    WGBAR();
    // C4
    READ_B(b1r, 1, 0);            // nh0(kt+1) from buf1
    STAGE_A(0, 1, kt + 2);        // (kt+2).Ah1
    WGBAR(); LGKM0();
    MFMA_Q(aB, b0r, 4, 0);
    WGBAR();
    // ======== tile kt+1 (buf1): aA=mh0(kt+1), b1r=nh0(kt+1)
    // C1'
    READ_B(b0r, 1, 1);            // nh1(kt+1)
    STAGE_B(0, 1, kt + 2);        // (kt+2).Bh1
    WGBAR(); LGKM0();
    MFMA_Q(aA, b1r, 0, 0);
    WGBAR();
    // C2'
    READ_A(aB, 1, 1);             // mh1(kt+1)
    STAGE_B(1, 0, kt + 3);        // (kt+3).Bh0
    WGBAR(); LGKM0();
    MFMA_Q(aA, b0r, 0, 2);
    VMW(4);                       // completes (kt+2).Ah1 and older
    WGBAR();
    // C3'
    READ_A(aA, 0, 0);             // mh0(kt+2) from buf0
    STAGE_A(1, 0, kt + 3);        // (kt+3).Ah0
    WGBAR(); LGKM0();
    MFMA_Q(aB, b0r, 4, 2);
    VMW(4);                       // completes (kt+2).Bh1 and older
    WGBAR();
    // C4'
    READ_B(b0r, 0, 0);            // nh0(kt+2) from buf0
    STAGE_A(1, 1, kt + 3);        // (kt+3).Ah1
    WGBAR(); LGKM0();
    MFMA_Q(aB, b1r, 4, 0);
    WGBAR();
  }

  // ======== tail: tile 62 (buf0) — only (63).Bh1 left to stage
  READ_B(b1r, 0, 1);
  STAGE_B(1, 1, NKT - 1);
  WGBAR(); LGKM0();
  MFMA_Q(aA, b0r, 0, 0);
  WGBAR();
  READ_A(aB, 0, 1);
  WGBAR(); LGKM0();
  MFMA_Q(aA, b1r, 0, 2);
  VMW(2);                         // completes (63).Ah1
  WGBAR();
  READ_A(aA, 1, 0);
  WGBAR(); LGKM0();
  MFMA_Q(aB, b1r, 4, 2);
  VMW(0);                         // completes (63).Bh1
  WGBAR();
  READ_B(b1r, 1, 0);
  WGBAR(); LGKM0();
  MFMA_Q(aB, b0r, 4, 0);
  WGBAR();
  // ======== tail: tile 63 (buf1)
  READ_B(b0r, 1, 1);
  WGBAR(); LGKM0();
  MFMA_Q(aA, b1r, 0, 0);
  WGBAR();
  READ_A(aB, 1, 1);
  WGBAR(); LGKM0();
  MFMA_Q(aA, b0r, 0, 2);
  WGBAR();
  MFMA_Q(aB, b0r, 4, 2);
  MFMA_Q(aB, b1r, 4, 0);

  // ---------------- epilogues (per wave: rows m0+wr*128+i*16+quad*4+r,
  //                               cols n0+wc*64+j*16+lm)
  if (MODE == 1) {  // RoPE -> [bh][s][d] bf16
#pragma unroll
    for (int i = 0; i < 8; ++i) {
      const int mbase = m0 + wr * 128 + i * 16 + quad * 4;
#pragma unroll
      for (int j = 0; j < 4; ++j) {
        const int n = n0 + wc * 64 + j * 16 + lm;
        const int hh = n >> 7, d = n & 127, ir = d >> 1;
#pragma unroll
        for (int r = 0; r < 4; ++r) {
          const int m = mbase + r;
          const int s = m & (S_ - 1);
          const int bb = m >> 11;
          float v = acc[i][j][r];
          float p = __shfl_xor(v, 1);
          float cv = fc[s * (HD_ / 2) + ir];
          float sv = fs[s * (HD_ / 2) + ir];
          float o = ((lane & 1) == 0) ? (v * cv - p * sv) : (p * sv + v * cv);
          float po = __shfl_xor(o, 1);
          if ((lane & 1) == 0) {
            unsigned pkt = rne_bf16(o) | (rne_bf16(po) << 16);
            size_t idx = (((size_t)(bb * H_ + hh) * S_ + s) * HD_ + d) >> 1;
            ((unsigned*)outB)[idx] = pkt;
          }
        }
      }
    }
  } else if (MODE == 3) {  // V^T -> [bh][d][s] bf16
#pragma unroll
    for (int i = 0; i < 8; ++i) {
      const int mbase = m0 + wr * 128 + i * 16 + quad * 4;
      const int sB = mbase & (S_ - 1);
      const int bb = mbase >> 11;
#pragma unroll
      for (int j = 0; j < 4; ++j) {
        const int n = n0 + wc * 64 + j * 16 + lm;
        const int hh = n >> 7, d = n & 127;
        uint2 pkt;
        pkt.x = rne_bf16(acc[i][j][0]) | (rne_bf16(acc[i][j][1]) << 16);
        pkt.y = rne_bf16(acc[i][j][2]) | (rne_bf16(acc[i][j][3]) << 16);
        size_t idx = ((size_t)(bb * H_ + hh) * HD_ + d) * S_ + sB;
        *(uint2*)&outB[idx] = pkt;
      }
    }
  } else {  // fp32 out [m][n]
#pragma unroll
    for (int i = 0; i < 8; ++i) {
      const int mbase = m0 + wr * 128 + i * 16 + quad * 4;
#pragma unroll
      for (int j = 0; j < 4; ++j) {
        const int n = n0 + wc * 64 + j * 16 + lm;
#pragma unroll
        for (int r = 0; r < 4; ++r) outF[(size_t)(mbase + r) * D_ + n] = acc[i][j][r];
      }
    }
  }
}

// ---------------------------------------------------------------- flash attention v3
// S^T formulation, Q frags in registers, BQ=128, BK=64. This round:
// + T5 setprio around MFMA clusters; + T13 defer-max (skip alpha/O-rescale
//   unless rowmax grew by >8/scale; P bounded by e^8, f32 headroom ok).
__global__ __launch_bounds__(256, 2) void flash_attn(
    const u16* __restrict__ Qb, const u16* __restrict__ Kb,
    const u16* __restrict__ Vtb, u16* __restrict__ attn) {
  __shared__ __align__(16) u16 lds[32768];

  const int tid = threadIdx.x;
  const int lane = tid & 63, w = tid >> 6;
  const int lm = lane & 15, quad = lane >> 4;
  const int qb = 15 - blockIdx.x;
  const int bh = blockIdx.y;
  const int bb = bh >> 5, h = bh & 31;

  const u16* Qg = Qb + ((size_t)bh * S_ + qb * 128 + w * 32) * HD_;
  const u16* Kg = Kb + (size_t)bh * S_ * HD_;
  const u16* Vg = Vtb + (size_t)bh * HD_ * S_;

  const u16* kp[4];
  const u16* vp[4];
#pragma unroll
  for (int it = 0; it < 4; ++it) {
    int c = tid + 256 * it;
    int kr = c >> 4, kc = (c & 15) ^ (kr & 15);
    kp[it] = Kg + (size_t)kr * HD_ + kc * 8;
    int vr = c >> 3, vc = (c & 7) ^ (vr & 7);
    vp[it] = Vg + (size_t)vr * S_ + vc * 8;
  }

  bf16x8 qf[2][4];
#pragma unroll
  for (int qt = 0; qt < 2; ++qt)
#pragma unroll
    for (int dk = 0; dk < 4; ++dk)
      qf[qt][dk] = *(const bf16x8*)(Qg + (size_t)(qt * 16 + lm) * HD_ + dk * 32 + quad * 8);

  f32x4 accO[8][2] = {};
  float m_run[2] = {-1e30f, -1e30f}, l_run[2] = {0.f, 0.f};
  const float scale = 0.08838834764831845f;  // 1/sqrt(128)
  const float THR = 90.50966799187809f;      // 8/scale
  const int nkt = 2 * qb + 2;
  const int qg0 = qb * 128 + w * 32;
  const int wq_max = qg0 + 31;

#pragma unroll
  for (int it = 0; it < 4; ++it) {
    async16(&lds[(tid + 256 * it) * 8], kp[it]);
    async16(&lds[8192 + (tid + 256 * it) * 8], vp[it]);
  }

  for (int kt = 0; kt < nkt; ++kt) {
    const int k0 = kt * 64;
    const int cur = (kt & 1) * 16384;
    __syncthreads();
    if (kt + 1 < nkt) {
      const int nxt = cur ^ 16384;
      const size_t koK = (size_t)(kt + 1) * 64 * HD_;
      const size_t koV = (size_t)(kt + 1) * 64;
#pragma unroll
      for (int it = 0; it < 4; ++it) {
        async16(&lds[nxt + (tid + 256 * it) * 8], kp[it] + koK);
        async16(&lds[nxt + 8192 + (tid + 256 * it) * 8], vp[it] + koV);
      }
    }
    if (k0 <= wq_max) {
      const u16* Ks = lds + cur;
      const u16* Vts = lds + cur + 8192;
      f32x4 sacc[2][4] = {};
#pragma unroll
      for (int dk = 0; dk < 4; ++dk) {
        bf16x8 kf[4];
#pragma unroll
        for (int t = 0; t < 4; ++t) {
          int row = (t >> 1) * 32 + ((lm >> 2) * 8) + ((t & 1) * 4) + (lm & 3);
          int ch = (dk * 4 + quad) ^ (row & 15);
          kf[t] = *(const bf16x8*)&Ks[(row * 16 + ch) * 8];
        }
        __builtin_amdgcn_s_setprio(1);
#pragma unroll
        for (int t = 0; t < 4; ++t)
#pragma unroll
          for (int qt = 0; qt < 2; ++qt)
            sacc[qt][t] = __builtin_amdgcn_mfma_f32_16x16x32_bf16(kf[t], qf[qt][dk], sacc[qt][t], 0, 0, 0);
        __builtin_amdgcn_s_setprio(0);
      }
      if (k0 + 63 > qg0) {
#pragma unroll
        for (int qt = 0; qt < 2; ++qt) {
          int q = qg0 + qt * 16 + lm;
#pragma unroll
          for (int t = 0; t < 4; ++t) {
            int kb = k0 + (t >> 1) * 32 + quad * 8 + (t & 1) * 4;
#pragma unroll
            for (int r = 0; r < 4; ++r)
              if (kb + r > q) sacc[qt][t][r] = -1e30f;
          }
        }
      }
      // ---- online softmax with defer-max (T13)
      float tmaxv[2];
#pragma unroll
      for (int qt = 0; qt < 2; ++qt) {
        float tmax = sacc[qt][0][0];
#pragma unroll
        for (int t = 0; t < 4; ++t)
#pragma unroll
          for (int r = 0; r < 4; ++r) tmax = fmaxf(tmax, sacc[qt][t][r]);
        tmax = fmaxf(tmax, __shfl_xor(tmax, 16));
        tmax = fmaxf(tmax, __shfl_xor(tmax, 32));
        tmaxv[qt] = tmax;
      }
      bool needl = (tmaxv[0] - m_run[0] > THR) || (tmaxv[1] - m_run[1] > THR);
      if (__any(needl)) {
#pragma unroll
        for (int qt = 0; qt < 2; ++qt) {
          float mnew = fmaxf(m_run[qt], tmaxv[qt]);
          float alpha = __expf((m_run[qt] - mnew) * scale);
          m_run[qt] = mnew;
          l_run[qt] *= alpha;
#pragma unroll
          for (int dt = 0; dt < 8; ++dt)
#pragma unroll
            for (int r = 0; r < 4; ++r) accO[dt][qt][r] *= alpha;
        }
      }
      bf16x8 pf[2][2];  // P^T frags [kc][qt]
#pragma unroll
      for (int qt = 0; qt < 2; ++qt) {
        float ms = m_run[qt] * scale;
        float rs = 0.f;
#pragma unroll
        for (int t = 0; t < 4; ++t)
#pragma unroll
          for (int r = 0; r < 4; ++r) {
            float p = __expf(fmaf(sacc[qt][t][r], scale, -ms));
            sacc[qt][t][r] = p;
            rs += p;
          }
        rs += __shfl_xor(rs, 16);
        rs += __shfl_xor(rs, 32);
        l_run[qt] += rs;
#pragma unroll
        for (int kc = 0; kc < 2; ++kc)
#pragma unroll
          for (int j = 0; j < 4; ++j) {
            pf[kc][qt][j]     = (__bf16)sacc[qt][2 * kc][j];
            pf[kc][qt][j + 4] = (__bf16)sacc[qt][2 * kc + 1][j];
          }
      }
      // ---- O^T += V^T * P^T
      __builtin_amdgcn_s_setprio(1);
#pragma unroll
      for (int kc = 0; kc < 2; ++kc)
#pragma unroll
        for (int dt = 0; dt < 8; ++dt) {
          int row = dt * 16 + lm;
          int ch = (kc * 4 + quad) ^ (row & 7);
          bf16x8 vf = *(const bf16x8*)&Vts[(row * 8 + ch) * 8];
#pragma unroll
          for (int qt = 0; qt < 2; ++qt)
            accO[dt][qt] = __builtin_amdgcn_mfma_f32_16x16x32_bf16(vf, pf[kc][qt], accO[dt][qt], 0, 0, 0);
        }
      __builtin_amdgcn_s_setprio(0);
    }
  }

  __syncthreads();
  u16* Et = lds;
  float inv[2] = {1.f / l_run[0], 1.f / l_run[1]};
#pragma unroll
  for (int dt = 0; dt < 8; ++dt)
#pragma unroll
    for (int qt = 0; qt < 2; ++qt) {
      const int rowq = w * 32 + qt * 16 + lm;
#pragma unroll
      for (int rp = 0; rp < 2; ++rp) {
        float a0 = accO[dt][qt][rp * 2] * inv[qt];
        float a1 = accO[dt][qt][rp * 2 + 1] * inv[qt];
        unsigned pkt = rne_bf16(a0) | (rne_bf16(a1) << 16);
        *(unsigned*)&Et[rowq * 136 + dt * 16 + quad * 4 + rp * 2] = pkt;
      }
    }
  const int rloc = w * 32 + (lane >> 1);
  const int half = lane & 1;
  const size_t gbase = (size_t)(bb * S_ + qb * 128 + rloc) * D_ + h * 128 + half * 64;
#pragma unroll
  for (int k = 0; k < 8; ++k) {
    uint4 vv = *(const uint4*)&Et[rloc * 136 + half * 64 + k * 8];
    *(uint4*)&attn[gbase + k * 8] = vv;
  }
}

// ---------------------------------------------------------------- launch
extern "C" void kernel_launch(void* const* d_in, const int* in_sizes, int n_in,
                              void* d_out, int out_size, void* d_ws, size_t ws_size,
                              hipStream_t stream) {
  const float* x  = (const float*)d_in[0];
  const float* fc = (const float*)d_in[1];
  const float* fs = (const float*)d_in[2];
  // d_in[3] = mask (causal, handled analytically)
  const float* wq = (const float*)d_in[4];
  const float* wk = (const float*)d_in[5];
  const float* wv = (const float*)d_in[6];
  const float* wo = (const float*)d_in[7];
  float* out = (float*)d_out;

  char* ws = (char*)d_ws;
  const size_t SZ = (size_t)B_ * S_ * D_ * 2;
  u16* xb  = (u16*)(ws);
  u16* wqb = (u16*)(ws + SZ);
  u16* wkb = (u16*)(ws + 2 * SZ);
  u16* wvb = (u16*)(ws + 3 * SZ);
  u16* Qb  = (u16*)(ws + 4 * SZ);
  u16* Kb  = (u16*)(ws + 5 * SZ);
  u16* Vtb = (u16*)(ws + 6 * SZ);
  u16* attn = xb;
  u16* wob  = wqb;

  dim3 blk(256);
  const int n8 = (B_ * S_ * D_) / 8;
  convert_bf16_x4<<<4 * (n8 / 256), blk, 0, stream>>>(x, wq, wk, wv, xb, wqb, wkb, wvb);

  dim3 blkG(512);
  dim3 g1(256);
  gemm_bt<1><<<g1, blkG, 0, stream>>>(xb, wqb, Qb, nullptr, fc, fs);
  gemm_bt<1><<<g1, blkG, 0, stream>>>(xb, wkb, Kb, nullptr, fc, fs);
  gemm_bt<3><<<g1, blkG, 0, stream>>>(xb, wvb, Vtb, nullptr, nullptr, nullptr);

  dim3 g2(16, 64);
  flash_attn<<<g2, blk, 0, stream>>>(Qb, Kb, Vtb, attn);

  convert_bf16<<<n8 / 256, blk, 0, stream>>>(wo, wob, n8);
  gemm_bt<4><<<g1, blkG, 0, stream>>>(attn, wob, nullptr, out, nullptr, nullptr);
}

// Round 4
// 1135.403 us; speedup vs baseline: 1.3813x; 1.3813x over previous
//
#include <hip/hip_runtime.h>
#include <hip/hip_bf16.h>
#include <math.h>

typedef unsigned short u16;
typedef __bf16 bf16x8 __attribute__((ext_vector_type(8)));
typedef float f32x4 __attribute__((ext_vector_type(4)));

#define B_  2
#define S_  2048
#define D_  4096
#define H_  32
#define HD_ 128

__device__ __forceinline__ unsigned rne_bf16(float x) {
  unsigned u = __float_as_uint(x);
  return (u + 0x7fffu + ((u >> 16) & 1u)) >> 16;
}

__device__ __forceinline__ void async16(void* lds_p, const void* g) {
  __builtin_amdgcn_global_load_lds(
      (__attribute__((address_space(1))) void*)(g),
      (__attribute__((address_space(3))) void*)(lds_p), 16, 0, 0);
}

// ---------------------------------------------------------------- convert
__global__ __launch_bounds__(256) void convert_bf16(
    const float* __restrict__ src, u16* __restrict__ dst, int n8) {
  int i = blockIdx.x * 256 + threadIdx.x;
  if (i >= n8) return;
  const float4* s = (const float4*)src + (size_t)i * 2;
  float4 a = s[0], b = s[1];
  uint4 o;
  o.x = rne_bf16(a.x) | (rne_bf16(a.y) << 16);
  o.y = rne_bf16(a.z) | (rne_bf16(a.w) << 16);
  o.z = rne_bf16(b.x) | (rne_bf16(b.y) << 16);
  o.w = rne_bf16(b.z) | (rne_bf16(b.w) << 16);
  ((uint4*)dst)[i] = o;
}

// fused 4-tensor convert: saves 3 launch gaps
__global__ __launch_bounds__(256) void convert_bf16_x4(
    const float* __restrict__ s0, const float* __restrict__ s1,
    const float* __restrict__ s2, const float* __restrict__ s3,
    u16* __restrict__ d0, u16* __restrict__ d1,
    u16* __restrict__ d2, u16* __restrict__ d3) {
  const int per = (B_ * S_ * D_) / 8 / 256;  // blocks per tensor
  const int which = blockIdx.x / per;
  const int i = (blockIdx.x % per) * 256 + threadIdx.x;
  const float* src = which == 0 ? s0 : which == 1 ? s1 : which == 2 ? s2 : s3;
  u16* dst = which == 0 ? d0 : which == 1 ? d1 : which == 2 ? d2 : d3;
  const float4* s = (const float4*)src + (size_t)i * 2;
  float4 a = s[0], b = s[1];
  uint4 o;
  o.x = rne_bf16(a.x) | (rne_bf16(a.y) << 16);
  o.y = rne_bf16(a.z) | (rne_bf16(a.w) << 16);
  o.z = rne_bf16(b.x) | (rne_bf16(b.y) << 16);
  o.w = rne_bf16(b.z) | (rne_bf16(b.w) << 16);
  ((uint4*)dst)[i] = o;
}

// ---------------------------------------------------------------- GEMM
// 128x128 tile, BK=32, 256 thr (4 waves). R2-verified base, upgraded from
// 2-buffer/__syncthreads (forced vmcnt(0) drain of a 1-step-old prefetch)
// to TRIPLE-BUFFER / prefetch-distance-2 / COUNTED vmcnt(4) + raw s_barrier.
// Per-thread ledger: each K-step issues 4 global_load_lds; after staging
// t+2 there are 8 outstanding {t+1:4, t+2:4}; vmcnt(4) retires exactly
// t+1's (issued TWO compute phases earlier -> latency covered). WAR: stage
// of buf[(t+2)%3] happens after the barrier that ends step t-1, whose
// readers (same buffer) fully retired before their MFMAs. Tail: vmcnt(0)
// at t=NT-2. 48 KB LDS -> 3 blocks/CU (m114 implicit overlap preserved).
// LDS chunk swizzle unchanged: slot s of row r holds chunk s^((r>>1)&3).
template <int MODE>
__global__ __launch_bounds__(256, 3) void gemm_bt(
    const u16* __restrict__ A, const u16* __restrict__ Bw,
    u16* __restrict__ outB, float* __restrict__ outF,
    const float* __restrict__ fc, const float* __restrict__ fs) {
  // buf p at p*8192 (u16): A tile 128x32 at +0, B tile at +4096. 48 KB.
  __shared__ __align__(16) u16 lds[24576];
  const int tid  = threadIdx.x;
  const int lane = tid & 63;
  const int wave = tid >> 6;
  const int lm   = lane & 15, quad = lane >> 4;
  const int mr = (wave >> 1) * 64, nc = (wave & 1) * 64;
  const int K = 4096;
  const int NT = K / 32;  // 128 K-steps

  // XCD-aware 2D-blocked swizzle (bijective; verified FETCH ~128MB in R2)
  const int bid = blockIdx.y * 32 + blockIdx.x;
  const int xg = bid & 7, l = bid >> 3;
  const int m0 = (((xg & 3) * 8) + (l & 7)) * 128;
  const int n0 = (((xg >> 2) * 16) + (l >> 3)) * 128;

  const int ca = tid, cb = tid + 256;
  const int ra = ca >> 2, ga = ((ca & 3) ^ ((ca >> 3) & 3)) * 8;
  const int rb = cb >> 2, gb = ((cb & 3) ^ ((cb >> 3) & 3)) * 8;
  const u16* Ag0 = A + (size_t)(m0 + ra) * K + ga;
  const u16* Ag1 = A + (size_t)(m0 + rb) * K + gb;
  const u16* Bg0 = Bw + (size_t)(n0 + ra) * K + ga;
  const u16* Bg1 = Bw + (size_t)(n0 + rb) * K + gb;

  const int koff = (quad ^ ((lm >> 1) & 3)) * 8;

  f32x4 acc[4][4] = {};

#define GSTAGE(BUF, T) do {                                   \
    u16* Ld_ = lds + (BUF) * 8192;                            \
    const size_t ko_ = (size_t)(T) * 32;                      \
    async16(&Ld_[ca * 8], Ag0 + ko_);                         \
    async16(&Ld_[cb * 8], Ag1 + ko_);                         \
    async16(&Ld_[4096 + ca * 8], Bg0 + ko_);                  \
    async16(&Ld_[4096 + cb * 8], Bg1 + ko_);                  \
  } while (0)

  // prologue: stage t0 -> buf0, t1 -> buf1 (8 outstanding)
  GSTAGE(0, 0);
  GSTAGE(1, 1);
  asm volatile("s_waitcnt vmcnt(4)" ::: "memory");  // t0 landed
  asm volatile("s_barrier" ::: "memory");

  int rbuf = 0, sbuf = 2;  // read buf, stage buf (= (t+2)%3)
  for (int t = 0; t < NT; ++t) {
    const u16* As = lds + rbuf * 8192;
    const u16* Bs = As + 4096;
    if (t + 2 < NT) GSTAGE(sbuf, t + 2);
    bf16x8 af[4], bfr[4];
#pragma unroll
    for (int i = 0; i < 4; ++i) af[i] = *(const bf16x8*)&As[(mr + i * 16 + lm) * 32 + koff];
#pragma unroll
    for (int j = 0; j < 4; ++j) bfr[j] = *(const bf16x8*)&Bs[(nc + j * 16 + lm) * 32 + koff];
#pragma unroll
    for (int i = 0; i < 4; ++i)
#pragma unroll
      for (int j = 0; j < 4; ++j)
        acc[i][j] = __builtin_amdgcn_mfma_f32_16x16x32_bf16(af[i], bfr[j], acc[i][j], 0, 0, 0);
    if (t < NT - 1) {
      if (t + 2 < NT) {
        asm volatile("s_waitcnt vmcnt(4)" ::: "memory");  // t+1 landed
      } else {
        asm volatile("s_waitcnt vmcnt(0)" ::: "memory");  // last tile landed
      }
      asm volatile("s_barrier" ::: "memory");
    }
    rbuf = rbuf == 2 ? 0 : rbuf + 1;
    sbuf = sbuf == 2 ? 0 : sbuf + 1;
  }
#undef GSTAGE

  if (MODE == 1) {  // RoPE -> [bh][s][d]
#pragma unroll
    for (int i = 0; i < 4; ++i) {
      const int mbase = m0 + mr + i * 16 + quad * 4;
#pragma unroll
      for (int j = 0; j < 4; ++j) {
        const int n = n0 + nc + j * 16 + lm;
        const int h = n >> 7, d = n & 127, ir = d >> 1;
#pragma unroll
        for (int r = 0; r < 4; ++r) {
          const int m = mbase + r;
          const int s = m & (S_ - 1);
          const int bb = m >> 11;
          float v = acc[i][j][r];
          float p = __shfl_xor(v, 1);
          float cv = fc[s * (HD_ / 2) + ir];
          float sv = fs[s * (HD_ / 2) + ir];
          float o = ((lane & 1) == 0) ? (v * cv - p * sv) : (p * sv + v * cv);
          float po = __shfl_xor(o, 1);
          if ((lane & 1) == 0) {
            unsigned pkt = rne_bf16(o) | (rne_bf16(po) << 16);
            size_t idx = (((size_t)(bb * H_ + h) * S_ + s) * HD_ + d) >> 1;
            ((unsigned*)outB)[idx] = pkt;
          }
        }
      }
    }
  } else if (MODE == 3) {  // V^T -> [bh][d][s]
#pragma unroll
    for (int i = 0; i < 4; ++i) {
      const int mbase = m0 + mr + i * 16 + quad * 4;
      const int s0 = mbase & (S_ - 1);
      const int bb = mbase >> 11;
#pragma unroll
      for (int j = 0; j < 4; ++j) {
        const int n = n0 + nc + j * 16 + lm;
        const int h = n >> 7, d = n & 127;
        uint2 pkt;
        pkt.x = rne_bf16(acc[i][j][0]) | (rne_bf16(acc[i][j][1]) << 16);
        pkt.y = rne_bf16(acc[i][j][2]) | (rne_bf16(acc[i][j][3]) << 16);
        size_t idx = ((size_t)(bb * H_ + h) * HD_ + d) * S_ + s0;
        *(uint2*)&outB[idx] = pkt;
      }
    }
  } else {  // fp32 out [m][n]
#pragma unroll
    for (int i = 0; i < 4; ++i) {
      const int mbase = m0 + mr + i * 16 + quad * 4;
#pragma unroll
      for (int j = 0; j < 4; ++j) {
        const int n = n0 + nc + j * 16 + lm;
#pragma unroll
        for (int r = 0; r < 4; ++r) outF[(size_t)(mbase + r) * D_ + n] = acc[i][j][r];
      }
    }
  }
}

// ---------------------------------------------------------------- flash attention v3
// S^T formulation, Q frags in registers, BQ=128, BK=64, T5 setprio,
// T13 defer-max (unchanged from R3 — attributed ~-20% there).
__global__ __launch_bounds__(256, 2) void flash_attn(
    const u16* __restrict__ Qb, const u16* __restrict__ Kb,
    const u16* __restrict__ Vtb, u16* __restrict__ attn) {
  __shared__ __align__(16) u16 lds[32768];

  const int tid = threadIdx.x;
  const int lane = tid & 63, w = tid >> 6;
  const int lm = lane & 15, quad = lane >> 4;
  const int qb = 15 - blockIdx.x;
  const int bh = blockIdx.y;
  const int bb = bh >> 5, h = bh & 31;

  const u16* Qg = Qb + ((size_t)bh * S_ + qb * 128 + w * 32) * HD_;
  const u16* Kg = Kb + (size_t)bh * S_ * HD_;
  const u16* Vg = Vtb + (size_t)bh * HD_ * S_;

  const u16* kp[4];
  const u16* vp[4];
#pragma unroll
  for (int it = 0; it < 4; ++it) {
    int c = tid + 256 * it;
    int kr = c >> 4, kc = (c & 15) ^ (kr & 15);
    kp[it] = Kg + (size_t)kr * HD_ + kc * 8;
    int vr = c >> 3, vc = (c & 7) ^ (vr & 7);
    vp[it] = Vg + (size_t)vr * S_ + vc * 8;
  }

  bf16x8 qf[2][4];
#pragma unroll
  for (int qt = 0; qt < 2; ++qt)
#pragma unroll
    for (int dk = 0; dk < 4; ++dk)
      qf[qt][dk] = *(const bf16x8*)(Qg + (size_t)(qt * 16 + lm) * HD_ + dk * 32 + quad * 8);

  f32x4 accO[8][2] = {};
  float m_run[2] = {-1e30f, -1e30f}, l_run[2] = {0.f, 0.f};
  const float scale = 0.08838834764831845f;  // 1/sqrt(128)
  const float THR = 90.50966799187809f;      // 8/scale
  const int nkt = 2 * qb + 2;
  const int qg0 = qb * 128 + w * 32;
  const int wq_max = qg0 + 31;

#pragma unroll
  for (int it = 0; it < 4; ++it) {
    async16(&lds[(tid + 256 * it) * 8], kp[it]);
    async16(&lds[8192 + (tid + 256 * it) * 8], vp[it]);
  }

  for (int kt = 0; kt < nkt; ++kt) {
    const int k0 = kt * 64;
    const int cur = (kt & 1) * 16384;
    __syncthreads();
    if (kt + 1 < nkt) {
      const int nxt = cur ^ 16384;
      const size_t koK = (size_t)(kt + 1) * 64 * HD_;
      const size_t koV = (size_t)(kt + 1) * 64;
#pragma unroll
      for (int it = 0; it < 4; ++it) {
        async16(&lds[nxt + (tid + 256 * it) * 8], kp[it] + koK);
        async16(&lds[nxt + 8192 + (tid + 256 * it) * 8], vp[it] + koV);
      }
    }
    if (k0 <= wq_max) {
      const u16* Ks = lds + cur;
      const u16* Vts = lds + cur + 8192;
      f32x4 sacc[2][4] = {};
#pragma unroll
      for (int dk = 0; dk < 4; ++dk) {
        bf16x8 kf[4];
#pragma unroll
        for (int t = 0; t < 4; ++t) {
          int row = (t >> 1) * 32 + ((lm >> 2) * 8) + ((t & 1) * 4) + (lm & 3);
          int ch = (dk * 4 + quad) ^ (row & 15);
          kf[t] = *(const bf16x8*)&Ks[(row * 16 + ch) * 8];
        }
        __builtin_amdgcn_s_setprio(1);
#pragma unroll
        for (int t = 0; t < 4; ++t)
#pragma unroll
          for (int qt = 0; qt < 2; ++qt)
            sacc[qt][t] = __builtin_amdgcn_mfma_f32_16x16x32_bf16(kf[t], qf[qt][dk], sacc[qt][t], 0, 0, 0);
        __builtin_amdgcn_s_setprio(0);
      }
      if (k0 + 63 > qg0) {
#pragma unroll
        for (int qt = 0; qt < 2; ++qt) {
          int q = qg0 + qt * 16 + lm;
#pragma unroll
          for (int t = 0; t < 4; ++t) {
            int kb = k0 + (t >> 1) * 32 + quad * 8 + (t & 1) * 4;
#pragma unroll
            for (int r = 0; r < 4; ++r)
              if (kb + r > q) sacc[qt][t][r] = -1e30f;
          }
        }
      }
      // ---- online softmax with defer-max (T13)
      float tmaxv[2];
#pragma unroll
      for (int qt = 0; qt < 2; ++qt) {
        float tmax = sacc[qt][0][0];
#pragma unroll
        for (int t = 0; t < 4; ++t)
#pragma unroll
          for (int r = 0; r < 4; ++r) tmax = fmaxf(tmax, sacc[qt][t][r]);
        tmax = fmaxf(tmax, __shfl_xor(tmax, 16));
        tmax = fmaxf(tmax, __shfl_xor(tmax, 32));
        tmaxv[qt] = tmax;
      }
      bool needl = (tmaxv[0] - m_run[0] > THR) || (tmaxv[1] - m_run[1] > THR);
      if (__any(needl)) {
#pragma unroll
        for (int qt = 0; qt < 2; ++qt) {
          float mnew = fmaxf(m_run[qt], tmaxv[qt]);
          float alpha = __expf((m_run[qt] - mnew) * scale);
          m_run[qt] = mnew;
          l_run[qt] *= alpha;
#pragma unroll
          for (int dt = 0; dt < 8; ++dt)
#pragma unroll
            for (int r = 0; r < 4; ++r) accO[dt][qt][r] *= alpha;
        }
      }
      bf16x8 pf[2][2];  // P^T frags [kc][qt]
#pragma unroll
      for (int qt = 0; qt < 2; ++qt) {
        float ms = m_run[qt] * scale;
        float rs = 0.f;
#pragma unroll
        for (int t = 0; t < 4; ++t)
#pragma unroll
          for (int r = 0; r < 4; ++r) {
            float p = __expf(fmaf(sacc[qt][t][r], scale, -ms));
            sacc[qt][t][r] = p;
            rs += p;
          }
        rs += __shfl_xor(rs, 16);
        rs += __shfl_xor(rs, 32);
        l_run[qt] += rs;
#pragma unroll
        for (int kc = 0; kc < 2; ++kc)
#pragma unroll
          for (int j = 0; j < 4; ++j) {
            pf[kc][qt][j]     = (__bf16)sacc[qt][2 * kc][j];
            pf[kc][qt][j + 4] = (__bf16)sacc[qt][2 * kc + 1][j];
          }
      }
      // ---- O^T += V^T * P^T
      __builtin_amdgcn_s_setprio(1);
#pragma unroll
      for (int kc = 0; kc < 2; ++kc)
#pragma unroll
        for (int dt = 0; dt < 8; ++dt) {
          int row = dt * 16 + lm;
          int ch = (kc * 4 + quad) ^ (row & 7);
          bf16x8 vf = *(const bf16x8*)&Vts[(row * 8 + ch) * 8];
#pragma unroll
          for (int qt = 0; qt < 2; ++qt)
            accO[dt][qt] = __builtin_amdgcn_mfma_f32_16x16x32_bf16(vf, pf[kc][qt], accO[dt][qt], 0, 0, 0);
        }
      __builtin_amdgcn_s_setprio(0);
    }
  }

  __syncthreads();
  u16* Et = lds;
  float inv[2] = {1.f / l_run[0], 1.f / l_run[1]};
#pragma unroll
  for (int dt = 0; dt < 8; ++dt)
#pragma unroll
    for (int qt = 0; qt < 2; ++qt) {
      const int rowq = w * 32 + qt * 16 + lm;
#pragma unroll
      for (int rp = 0; rp < 2; ++rp) {
        float a0 = accO[dt][qt][rp * 2] * inv[qt];
        float a1 = accO[dt][qt][rp * 2 + 1] * inv[qt];
        unsigned pkt = rne_bf16(a0) | (rne_bf16(a1) << 16);
        *(unsigned*)&Et[rowq * 136 + dt * 16 + quad * 4 + rp * 2] = pkt;
      }
    }
  const int rloc = w * 32 + (lane >> 1);
  const int half = lane & 1;
  const size_t gbase = (size_t)(bb * S_ + qb * 128 + rloc) * D_ + h * 128 + half * 64;
#pragma unroll
  for (int k = 0; k < 8; ++k) {
    uint4 vv = *(const uint4*)&Et[rloc * 136 + half * 64 + k * 8];
    *(uint4*)&attn[gbase + k * 8] = vv;
  }
}

// ---------------------------------------------------------------- launch
extern "C" void kernel_launch(void* const* d_in, const int* in_sizes, int n_in,
                              void* d_out, int out_size, void* d_ws, size_t ws_size,
                              hipStream_t stream) {
  const float* x  = (const float*)d_in[0];
  const float* fc = (const float*)d_in[1];
  const float* fs = (const float*)d_in[2];
  // d_in[3] = mask (causal, handled analytically)
  const float* wq = (const float*)d_in[4];
  const float* wk = (const float*)d_in[5];
  const float* wv = (const float*)d_in[6];
  const float* wo = (const float*)d_in[7];
  float* out = (float*)d_out;

  char* ws = (char*)d_ws;
  const size_t SZ = (size_t)B_ * S_ * D_ * 2;
  u16* xb  = (u16*)(ws);
  u16* wqb = (u16*)(ws + SZ);
  u16* wkb = (u16*)(ws + 2 * SZ);
  u16* wvb = (u16*)(ws + 3 * SZ);
  u16* Qb  = (u16*)(ws + 4 * SZ);
  u16* Kb  = (u16*)(ws + 5 * SZ);
  u16* Vtb = (u16*)(ws + 6 * SZ);
  u16* attn = xb;
  u16* wob  = wqb;

  dim3 blk(256);
  const int n8 = (B_ * S_ * D_) / 8;
  convert_bf16_x4<<<4 * (n8 / 256), blk, 0, stream>>>(x, wq, wk, wv, xb, wqb, wkb, wvb);

  dim3 g1(32, 32);
  gemm_bt<1><<<g1, blk, 0, stream>>>(xb, wqb, Qb, nullptr, fc, fs);
  gemm_bt<1><<<g1, blk, 0, stream>>>(xb, wkb, Kb, nullptr, fc, fs);
  gemm_bt<3><<<g1, blk, 0, stream>>>(xb, wvb, Vtb, nullptr, nullptr, nullptr);

  dim3 g2(16, 64);
  flash_attn<<<g2, blk, 0, stream>>>(Qb, Kb, Vtb, attn);

  convert_bf16<<<n8 / 256, blk, 0, stream>>>(wo, wob, n8);
  gemm_bt<4><<<g1, blk, 0, stream>>>(attn, wob, nullptr, out, nullptr, nullptr);
}